// Round 1
// baseline (413.706 us; speedup 1.0000x reference)
//
#include <hip/hip_runtime.h>
#include <math.h>

#define NROWS 65536
#define DIM   256
#define NCLS  512
#define NCHUNK 16
#define NDSL   8
#define DSLW   (DIM / NDSL)               // 32
#define ROWS_PER_CHUNK (NROWS / NCHUNK)   // 4096
#define TR 32
#define KC 16
#define NBLK_MAIN (NROWS / TR)            // 2048

// ws layout (float offsets):
//   partials: NCHUNK*NCLS*DIM            = 2,097,152 floats (8 MB)
//   qt      : DIM*NCLS                   =   131,072 floats (512 KB)
//   lossp   : NBLK_MAIN                  =     2,048 floats
#define WS_PARTIALS 0
#define WS_QT  (NCHUNK * NCLS * DIM)
#define WS_LOSSP (WS_QT + DIM * NCLS)

// ---------------- kernel 1: partial class sums (LDS atomics) ----------------
__global__ __launch_bounds__(256) void k_partial_sums(
    const float* __restrict__ x, const int* __restrict__ tgt,
    float* __restrict__ partials) {
  __shared__ float lsum[NCLS * DSLW];   // 64 KB
  const int b     = blockIdx.x;
  const int dsl   = b & (NDSL - 1);
  const int chunk = b >> 3;             // NDSL == 8
  const int tid   = threadIdx.x;
  for (int i = tid; i < NCLS * DSLW; i += 256) lsum[i] = 0.f;
  __syncthreads();
  const int d     = tid & 31;
  const int rsub  = tid >> 5;           // 0..7
  const int rbase = chunk * ROWS_PER_CHUNK;
  #pragma unroll 4
  for (int it = 0; it < ROWS_PER_CHUNK / 8; ++it) {
    const int row = rbase + it * 8 + rsub;
    const int c   = tgt[row];
    const float v = x[row * DIM + dsl * DSLW + d];
    atomicAdd(&lsum[c * DSLW + d], v);
  }
  __syncthreads();
  for (int i = tid; i < NCLS * DSLW; i += 256) {
    const int c  = i >> 5;
    const int dd = i & 31;
    partials[(chunk * NCLS + c) * DIM + dsl * DSLW + dd] = lsum[i];
  }
}

// ------------- kernel 2: reduce partials -> normalized protos^T -------------
// counts cancel under normalization: q_c = sums_c / |sums_c|
__global__ __launch_bounds__(256) void k_protos(
    const float* __restrict__ partials, float* __restrict__ qt) {
  const int c = blockIdx.x;     // class
  const int d = threadIdx.x;    // dim (256 threads == DIM)
  float s = 0.f;
  #pragma unroll
  for (int ch = 0; ch < NCHUNK; ++ch)
    s += partials[(ch * NCLS + c) * DIM + d];
  float sq = s * s;
  #pragma unroll
  for (int off = 1; off < 64; off <<= 1) sq += __shfl_xor(sq, off, 64);
  __shared__ float wsum[4];
  __shared__ float ninv_s;
  const int lane = d & 63, w = d >> 6;
  if (lane == 0) wsum[w] = sq;
  __syncthreads();
  if (d == 0) ninv_s = rsqrtf(fmaxf(wsum[0] + wsum[1] + wsum[2] + wsum[3], 1e-30f));
  __syncthreads();
  qt[d * NCLS + c] = s * ninv_s;   // QT[D][C], row-major
}

// --------- kernel 3: fused GEMM (x . q^T) + row log-softmax + NLL -----------
__global__ __launch_bounds__(256, 2) void k_main(
    const float* __restrict__ x, const int* __restrict__ tgt,
    const float* __restrict__ qt, float* __restrict__ lossp) {
  __shared__ float ldsA[TR][DIM + 4];   // 32 x 260 f32 = 33,280 B
  __shared__ float ldsB[KC][NCLS];      // 16 x 512 f32 = 32,768 B
  __shared__ float rninv[TR];
  __shared__ int   ltgt[TR];
  __shared__ float wloss[4];

  const int tid = threadIdx.x;
  const int i0  = blockIdx.x * TR;

  // stage A (32 rows x 256 dims), float4 coalesced
  #pragma unroll
  for (int i = 0; i < 8; ++i) {
    const int idx4 = tid + i * 256;          // 0..2047 float4s
    const int r    = idx4 >> 6;              // 0..31
    const int dd   = (idx4 & 63) * 4;        // 0..252
    const float4 v = *reinterpret_cast<const float4*>(&x[(size_t)(i0 + r) * DIM + dd]);
    *reinterpret_cast<float4*>(&ldsA[r][dd]) = v;
  }
  if (tid < TR) ltgt[tid] = tgt[i0 + tid];
  __syncthreads();

  // per-row inverse norms (8 threads per row)
  {
    const int row = tid >> 3, g = tid & 7;
    float s = 0.f;
    #pragma unroll
    for (int j = 0; j < DIM / 8; ++j) {
      const float v = ldsA[row][g + 8 * j];
      s += v * v;
    }
    s += __shfl_xor(s, 1, 64);
    s += __shfl_xor(s, 2, 64);
    s += __shfl_xor(s, 4, 64);
    if (g == 0) rninv[row] = rsqrtf(fmaxf(s, 1e-30f));
  }

  const int tc = tid & 63;   // class group: classes tc*8 .. tc*8+7
  const int tr = tid >> 6;   // wave id: rows tr*8 .. tr*8+7
  float acc[8][8];
  #pragma unroll
  for (int r = 0; r < 8; ++r)
    #pragma unroll
    for (int c = 0; c < 8; ++c) acc[r][c] = 0.f;

  for (int kt = 0; kt < DIM / KC; ++kt) {
    __syncthreads();
    // stage B tile: KC x NCLS floats, float4 coalesced
    #pragma unroll
    for (int i = 0; i < 8; ++i) {
      const int idx4 = tid + i * 256;
      const int flat = idx4 * 4;
      const int kk   = flat >> 9;        // /512
      const int cc   = flat & 511;
      *reinterpret_cast<float4*>(&ldsB[kk][cc]) =
        *reinterpret_cast<const float4*>(&qt[(size_t)(kt * KC + kk) * NCLS + cc]);
    }
    __syncthreads();
    #pragma unroll
    for (int kk = 0; kk < KC; ++kk) {
      const int k = kt * KC + kk;
      float a[8], bb[8];
      #pragma unroll
      for (int r = 0; r < 8; ++r) a[r] = ldsA[tr * 8 + r][k];
      #pragma unroll
      for (int c = 0; c < 8; ++c) bb[c] = ldsB[kk][tc * 8 + c];
      #pragma unroll
      for (int r = 0; r < 8; ++r)
        #pragma unroll
        for (int c = 0; c < 8; ++c)
          acc[r][c] = fmaf(a[r], bb[c], acc[r][c]);
    }
  }
  __syncthreads();

  // epilogue: per-row (wave-wide) max, sum-exp, target pick
  float myloss = 0.f;
  #pragma unroll
  for (int rr = 0; rr < 8; ++rr) {
    const int rloc = tr * 8 + rr;
    const float rn = rninv[rloc];
    float av[8];
    float mx = -1e30f;
    #pragma unroll
    for (int c = 0; c < 8; ++c) { av[c] = acc[rr][c] * rn; mx = fmaxf(mx, av[c]); }
    #pragma unroll
    for (int off = 32; off >= 1; off >>= 1) mx = fmaxf(mx, __shfl_xor(mx, off, 64));
    float s = 0.f;
    #pragma unroll
    for (int c = 0; c < 8; ++c) s += __expf(av[c] - mx);
    #pragma unroll
    for (int off = 32; off >= 1; off >>= 1) s += __shfl_xor(s, off, 64);
    const int t = ltgt[rloc];
    float pick = 0.f;
    #pragma unroll
    for (int c = 0; c < 8; ++c) pick = ((t & 7) == c) ? av[c] : pick;
    const float simt = __shfl(pick, t >> 3, 64);
    myloss += mx + __logf(s) - simt;   // = logsumexp - sim_target
  }
  if (tc == 0) wloss[tr] = myloss;     // wave-uniform after reductions
  __syncthreads();
  if (tid == 0) lossp[blockIdx.x] = wloss[0] + wloss[1] + wloss[2] + wloss[3];
}

// ---------------------- kernel 4: final mean reduction ----------------------
__global__ __launch_bounds__(256) void k_finalize(
    const float* __restrict__ lossp, float* __restrict__ out) {
  const int tid = threadIdx.x;
  float s = 0.f;
  for (int i = tid; i < NBLK_MAIN; i += 256) s += lossp[i];
  #pragma unroll
  for (int off = 32; off >= 1; off >>= 1) s += __shfl_xor(s, off, 64);
  __shared__ float ws4[4];
  if ((tid & 63) == 0) ws4[tid >> 6] = s;
  __syncthreads();
  if (tid == 0) out[0] = (ws4[0] + ws4[1] + ws4[2] + ws4[3]) / (float)NROWS;
}

extern "C" void kernel_launch(void* const* d_in, const int* in_sizes, int n_in,
                              void* d_out, int out_size, void* d_ws, size_t ws_size,
                              hipStream_t stream) {
  const float* x   = (const float*)d_in[0];
  const int*   tgt = (const int*)d_in[1];
  float* ws       = (float*)d_ws;
  float* partials = ws + WS_PARTIALS;
  float* qt       = ws + WS_QT;
  float* lossp    = ws + WS_LOSSP;

  k_partial_sums<<<NCHUNK * NDSL, 256, 0, stream>>>(x, tgt, partials);
  k_protos<<<NCLS, 256, 0, stream>>>(partials, qt);
  k_main<<<NBLK_MAIN, 256, 0, stream>>>(x, tgt, qt, lossp);
  k_finalize<<<1, 256, 0, stream>>>(lossp, (float*)d_out);
}

// Round 2
// 83.006 us; speedup vs baseline: 4.9840x; 4.9840x over previous
//
#include <hip/hip_runtime.h>
#include <math.h>

#define NROWS 65536
#define DIM   256
#define NCLS  512
#define CPW   128                 // rows per class = NROWS/NCLS
#define BM    64                  // rows per k_main block
#define NBLK_MAIN (NROWS / BM)    // 1024

// ws layout (float offsets)
#define WS_CNT   0                // 512 ints
#define WS_IDX   512              // 65536 ints
#define WS_QPACK 66048            // 131072 ushorts (64 KB), 16B-aligned
#define WS_LOSSP 131584           // 1024 floats

typedef float f32x4  __attribute__((ext_vector_type(4)));
typedef short bf16x8 __attribute__((ext_vector_type(8)));

__device__ inline unsigned short f2bf(float f) {
  unsigned u = __float_as_uint(f);
  u += 0x7FFFu + ((u >> 16) & 1u);      // RNE (inputs finite)
  return (unsigned short)(u >> 16);
}
__device__ inline unsigned pack2(float a, float b) {
  return (unsigned)f2bf(a) | ((unsigned)f2bf(b) << 16);
}

// ---------------- kernel 0: zero class cursors ----------------
__global__ __launch_bounds__(512) void k_zero(int* __restrict__ cnt) {
  cnt[threadIdx.x] = 0;
}

// ---------------- kernel 1: scatter row indices by class ----------------
__global__ __launch_bounds__(256) void k_scatter(
    const int* __restrict__ tgt, int* __restrict__ cnt, int* __restrict__ idx) {
  const int row = blockIdx.x * 256 + threadIdx.x;
  const int c = tgt[row];
  const int p = atomicAdd(&cnt[c], 1);
  if (p < CPW) idx[c * CPW + p] = row;
}

// ------- kernel 2: per-class sum + normalize + pack bf16 B-fragments -------
// qpack layout: [k/8][class][8] bf16 -> each lane's MFMA-B frag is 16B contig
__global__ __launch_bounds__(256) void k_csum(
    const float* __restrict__ x, const int* __restrict__ idx,
    unsigned short* __restrict__ qpack) {
  __shared__ int sidx[CPW];
  __shared__ float wsum[4];
  __shared__ float ninv_s;
  const int c = blockIdx.x, d = threadIdx.x;
  if (d < CPW) sidx[d] = idx[c * CPW + d];
  __syncthreads();
  float s = 0.f;
  #pragma unroll 8
  for (int j = 0; j < CPW; ++j) s += x[(size_t)sidx[j] * DIM + d];
  float sq = s * s;
  #pragma unroll
  for (int off = 1; off < 64; off <<= 1) sq += __shfl_xor(sq, off, 64);
  if ((d & 63) == 0) wsum[d >> 6] = sq;
  __syncthreads();
  if (d == 0) ninv_s = rsqrtf(fmaxf(wsum[0] + wsum[1] + wsum[2] + wsum[3], 1e-30f));
  __syncthreads();
  qpack[((d >> 3) * NCLS + c) * 8 + (d & 7)] = f2bf(s * ninv_s);
}

// --------- kernel 3: bf16 MFMA GEMM + row log-softmax + NLL -----------
// block: 512 thr = 8 waves (2 row-groups x 4 col-groups), BM=64 rows, all 512 cols
__global__ __launch_bounds__(512) void k_main(
    const float* __restrict__ x, const int* __restrict__ tgt,
    const unsigned short* __restrict__ qpack, float* __restrict__ lossp) {
  __shared__ unsigned short apack[32 * BM * 8];   // [kgroup][row][8] bf16, 32 KB
  __shared__ float pmax[4][BM];
  __shared__ float psum[4][BM];
  __shared__ float simt[BM];
  __shared__ int   ltgt[BM];

  const int tid = threadIdx.x;
  const int i0  = blockIdx.x * BM;

  // ---- stage: load 64x256 f32, normalize rows, cvt bf16 -> LDS (k-packed)
  {
    const int row  = tid >> 3;          // 0..63
    const int part = tid & 7;           // 32 dims each
    float4 v[8];
    const float4* xr = reinterpret_cast<const float4*>(
        x + (size_t)(i0 + row) * DIM + part * 32);
    #pragma unroll
    for (int j = 0; j < 8; ++j) v[j] = xr[j];
    float ss = 0.f;
    #pragma unroll
    for (int j = 0; j < 8; ++j)
      ss += v[j].x * v[j].x + v[j].y * v[j].y + v[j].z * v[j].z + v[j].w * v[j].w;
    ss += __shfl_xor(ss, 1, 64);
    ss += __shfl_xor(ss, 2, 64);
    ss += __shfl_xor(ss, 4, 64);        // partners share row (row = tid>>3)
    const float rn = rsqrtf(fmaxf(ss, 1e-30f));
    #pragma unroll
    for (int jj = 0; jj < 4; ++jj) {    // 4 chunks of 8 dims
      uint4 w;
      w.x = pack2(v[2*jj].x * rn,   v[2*jj].y * rn);
      w.y = pack2(v[2*jj].z * rn,   v[2*jj].w * rn);
      w.z = pack2(v[2*jj+1].x * rn, v[2*jj+1].y * rn);
      w.w = pack2(v[2*jj+1].z * rn, v[2*jj+1].w * rn);
      const int kg = part * 4 + jj;     // k-group 0..31
      *reinterpret_cast<uint4*>(&apack[(kg * BM + row) * 8]) = w;
    }
  }
  if (tid < BM) ltgt[tid] = tgt[i0 + tid];
  __syncthreads();

  const int w    = tid >> 6;
  const int lane = tid & 63;
  const int wr = w >> 2, wc = w & 3;    // wave row-group / col-group
  const int lg = lane >> 4, l15 = lane & 15;

  f32x4 acc[2][8];
  #pragma unroll
  for (int m = 0; m < 2; ++m)
    #pragma unroll
    for (int n = 0; n < 8; ++n) acc[m][n] = (f32x4)0.f;

  const bf16x8* ap = reinterpret_cast<const bf16x8*>(apack);
  const bf16x8* bp = reinterpret_cast<const bf16x8*>(qpack);
  const int bbase = wc * 128 + l15;     // + n*16 per frag

  bf16x8 b0[8], b1[8];
  #pragma unroll
  for (int n = 0; n < 8; ++n) b0[n] = bp[lg * NCLS + bbase + n * 16];

  #pragma unroll 1
  for (int kk = 0; kk < 8; kk += 2) {
    #pragma unroll
    for (int n = 0; n < 8; ++n)
      b1[n] = bp[((kk + 1) * 4 + lg) * NCLS + bbase + n * 16];
    {
      const bf16x8 a0 = ap[(kk * 4 + lg) * BM + wr * 32 + l15];
      const bf16x8 a1 = ap[(kk * 4 + lg) * BM + wr * 32 + 16 + l15];
      #pragma unroll
      for (int n = 0; n < 8; ++n) {
        acc[0][n] = __builtin_amdgcn_mfma_f32_16x16x32_bf16(a0, b0[n], acc[0][n], 0, 0, 0);
        acc[1][n] = __builtin_amdgcn_mfma_f32_16x16x32_bf16(a1, b0[n], acc[1][n], 0, 0, 0);
      }
    }
    const int k2 = (kk + 2) & 7;        // wrap avoids branch; last prefetch unused
    #pragma unroll
    for (int n = 0; n < 8; ++n)
      b0[n] = bp[(k2 * 4 + lg) * NCLS + bbase + n * 16];
    {
      const bf16x8 a0 = ap[((kk + 1) * 4 + lg) * BM + wr * 32 + l15];
      const bf16x8 a1 = ap[((kk + 1) * 4 + lg) * BM + wr * 32 + 16 + l15];
      #pragma unroll
      for (int n = 0; n < 8; ++n) {
        acc[0][n] = __builtin_amdgcn_mfma_f32_16x16x32_bf16(a0, b1[n], acc[0][n], 0, 0, 0);
        acc[1][n] = __builtin_amdgcn_mfma_f32_16x16x32_bf16(a1, b1[n], acc[1][n], 0, 0, 0);
      }
    }
  }

  // ---- epilogue: per-row softmax over 512 cols (acc holds cosine sims)
  // C layout: col = wc*128 + n*16 + l15 ; row = wr*32 + m*16 + lg*4 + reg
  #pragma unroll
  for (int m = 0; m < 2; ++m) {
    #pragma unroll
    for (int reg = 0; reg < 4; ++reg) {
      float mx = acc[m][0][reg];
      #pragma unroll
      for (int n = 1; n < 8; ++n) mx = fmaxf(mx, acc[m][n][reg]);
      mx = fmaxf(mx, __shfl_xor(mx, 1, 64));
      mx = fmaxf(mx, __shfl_xor(mx, 2, 64));
      mx = fmaxf(mx, __shfl_xor(mx, 4, 64));
      mx = fmaxf(mx, __shfl_xor(mx, 8, 64));
      const int r = wr * 32 + m * 16 + lg * 4 + reg;
      if (l15 == 0) pmax[wc][r] = mx;
    }
  }
  __syncthreads();
  #pragma unroll
  for (int m = 0; m < 2; ++m) {
    #pragma unroll
    for (int reg = 0; reg < 4; ++reg) {
      const int r = wr * 32 + m * 16 + lg * 4 + reg;
      const float gm = fmaxf(fmaxf(pmax[0][r], pmax[1][r]),
                             fmaxf(pmax[2][r], pmax[3][r]));
      float s = 0.f;
      #pragma unroll
      for (int n = 0; n < 8; ++n) s += __expf(acc[m][n][reg] - gm);
      s += __shfl_xor(s, 1, 64);
      s += __shfl_xor(s, 2, 64);
      s += __shfl_xor(s, 4, 64);
      s += __shfl_xor(s, 8, 64);
      if (l15 == 0) psum[wc][r] = s;
      const int t = ltgt[r];
      if ((t >> 7) == wc && (t & 15) == l15) {
        const int nt = (t >> 4) & 7;
        float pv = acc[m][0][reg];
        #pragma unroll
        for (int n = 1; n < 8; ++n) pv = (nt == n) ? acc[m][n][reg] : pv;
        simt[r] = pv;
      }
    }
  }
  __syncthreads();
  if (tid < BM) {
    const int r = tid;
    const float gm = fmaxf(fmaxf(pmax[0][r], pmax[1][r]),
                           fmaxf(pmax[2][r], pmax[3][r]));
    const float sum = psum[0][r] + psum[1][r] + psum[2][r] + psum[3][r];
    float lr = __logf(sum) + gm - simt[r];
    lr += __shfl_xor(lr, 1, 64);
    lr += __shfl_xor(lr, 2, 64);
    lr += __shfl_xor(lr, 4, 64);
    lr += __shfl_xor(lr, 8, 64);
    lr += __shfl_xor(lr, 16, 64);
    lr += __shfl_xor(lr, 32, 64);
    if (tid == 0) lossp[blockIdx.x] = lr;
  }
}

// ---------------------- kernel 4: final mean reduction ----------------------
__global__ __launch_bounds__(256) void k_finalize(
    const float* __restrict__ lossp, float* __restrict__ out) {
  const int tid = threadIdx.x;
  float s = 0.f;
  for (int i = tid; i < NBLK_MAIN; i += 256) s += lossp[i];
  #pragma unroll
  for (int off = 32; off >= 1; off >>= 1) s += __shfl_xor(s, off, 64);
  __shared__ float ws4[4];
  if ((tid & 63) == 0) ws4[tid >> 6] = s;
  __syncthreads();
  if (tid == 0) out[0] = (ws4[0] + ws4[1] + ws4[2] + ws4[3]) / (float)NROWS;
}

extern "C" void kernel_launch(void* const* d_in, const int* in_sizes, int n_in,
                              void* d_out, int out_size, void* d_ws, size_t ws_size,
                              hipStream_t stream) {
  const float* x   = (const float*)d_in[0];
  const int*   tgt = (const int*)d_in[1];
  float* ws = (float*)d_ws;
  int*   cnt   = (int*)(ws + WS_CNT);
  int*   idx   = (int*)(ws + WS_IDX);
  unsigned short* qpack = (unsigned short*)(ws + WS_QPACK);
  float* lossp = ws + WS_LOSSP;

  k_zero<<<1, 512, 0, stream>>>(cnt);
  k_scatter<<<NROWS / 256, 256, 0, stream>>>(tgt, cnt, idx);
  k_csum<<<NCLS, 256, 0, stream>>>(x, idx, qpack);
  k_main<<<NBLK_MAIN, 512, 0, stream>>>(x, tgt, qpack, lossp);
  k_finalize<<<1, 256, 0, stream>>>(lossp, (float*)d_out);
}